// Round 4
// baseline (168.142 us; speedup 1.0000x reference)
//
#include <hip/hip_runtime.h>
#include <math.h>

// Problem constants (B=4, H=8, N=4096, R=d=64)
#define NB 4
#define NH 8
#define BHN 32
#define SN 4096
#define RR 64
#define REGC 0.1f

#define MCH 32        // k_main chunks per bh (grid 1024 = 4 blocks/CU)
#define MROWS 128     // rows per k_main block (2 stages of 64)
#define XCH 32        // k_xq chunks per bh (grid 1024)
#define XROWS 128     // rows per k_xq block (2 stages of 64)

typedef short s16x8 __attribute__((ext_vector_type(8)));
typedef float f32x4 __attribute__((ext_vector_type(4)));

__device__ __forceinline__ float wave_sum(float v) {     // loss reductions only
    #pragma unroll
    for (int off = 32; off; off >>= 1) v += __shfl_xor(v, off, 64);
    return v;
}
// 64-lane sum: 4 DPP row-rotate adds (VALU pipe) + 2 shuffles (LDS pipe)
__device__ __forceinline__ float wave_sum64(float v) {
    v += __int_as_float(__builtin_amdgcn_update_dpp(0, __float_as_int(v), 0x121, 0xf, 0xf, true));
    v += __int_as_float(__builtin_amdgcn_update_dpp(0, __float_as_int(v), 0x122, 0xf, 0xf, true));
    v += __int_as_float(__builtin_amdgcn_update_dpp(0, __float_as_int(v), 0x124, 0xf, 0xf, true));
    v += __int_as_float(__builtin_amdgcn_update_dpp(0, __float_as_int(v), 0x128, 0xf, 0xf, true));
    v += __shfl_xor(v, 16, 64);
    v += __shfl_xor(v, 32, 64);
    return v;
}
// 8-lane octet sum (lanes sharing l>>3): quad_perm xor1, xor2 (VALU) + shfl 4
__device__ __forceinline__ float octet_sum(float v) {
    v += __int_as_float(__builtin_amdgcn_update_dpp(0, __float_as_int(v), 0xB1, 0xf, 0xf, true));
    v += __int_as_float(__builtin_amdgcn_update_dpp(0, __float_as_int(v), 0x4E, 0xf, 0xf, true));
    v += __shfl_xor(v, 4, 64);
    return v;
}
// fast reciprocal: v_rcp_f32 (~1ulp) instead of full IEEE div sequence
__device__ __forceinline__ float fastrcp(float x) {
    float r; asm("v_rcp_f32 %0, %1" : "=v"(r) : "v"(x)); return r;
}
__device__ __forceinline__ unsigned short f2bf(float x) {
    unsigned int u = __float_as_uint(x);
    u += 0x7FFFu + ((u >> 16) & 1u);
    return (unsigned short)(u >> 16);
}
__device__ __forceinline__ float bf2f(unsigned short h) {
    return __uint_as_float(((unsigned int)h) << 16);
}
__device__ __forceinline__ unsigned int packbf(float a, float b) {
    return (unsigned int)f2bf(a) | ((unsigned int)f2bf(b) << 16);
}
__device__ __forceinline__ s16x8 ldfrag(const unsigned int* p) {
    uint4 r = *(const uint4*)p;
    return __builtin_bit_cast(s16x8, r);
}
// row-major [64 rows][64 bf16], rowstride 32 uints, 16B-block XOR swizzle
__device__ __forceinline__ int swz(int row, int blk) {
    return (row << 5) + (((blk ^ (row & 7))) << 2);
}
__device__ __forceinline__ uint4 pack8(const float* x) {
    return make_uint4(packbf(x[0], x[1]), packbf(x[2], x[3]),
                      packbf(x[4], x[5]), packbf(x[6], x[7]));
}

// ---- fused main reduction: single-buffer LDS (24 KB) + grid 1024 = 4 blk/CU ----
// planes (uints): Ph=0, Vh=2048, Qh=4096; total 6144 uints (24 KB)
// launch_bounds(512,4): 128-VGPR cap; compiler lands ~64, no spill (round 3).
// Round 2's failure with this structure was purely the (512,8)->32-VGPR spill.
#define PH 0
#define VH 2048
#define QH 4096
__launch_bounds__(512, 4)
__global__ void k_main(const float* __restrict__ U, const float* __restrict__ sv,
                       const float* __restrict__ V, const float* __restrict__ mask,
                       float* __restrict__ ktv_part, float* __restrict__ symk_part,
                       float* __restrict__ symq_part, float* __restrict__ colsum_part) {
    __shared__ __align__(16) unsigned int sm[6144];   // 24 KB
    const int chunk = blockIdx.x, bh = blockIdx.y, b = bh >> 3;
    const int t = threadIdx.x, l = t & 63, w = t >> 6;
    const int r15 = l & 15, quad = l >> 4;
    const int ni = w & 3, mi0 = (w >> 2) << 1;
    const size_t rowbase = (size_t)bh * SN * RR;
    const int row0 = chunk * MROWS;

    float csum = 0.0f;
    f32x4 aKV[2], aSK[2], aSQ[2];
    #pragma unroll
    for (int j = 0; j < 2; j++) {
        aKV[j] = (f32x4){0.f, 0.f, 0.f, 0.f};
        aSK[j] = (f32x4){0.f, 0.f, 0.f, 0.f};
        aSQ[j] = (f32x4){0.f, 0.f, 0.f, 0.f};
    }

    float bu[2][8], bx[2][8], bv[2][8], bm[2][8];
    #pragma unroll
    for (int i = 0; i < 8; i++) {
        const size_t off = rowbase + (size_t)(row0 + 8 * w + i) * RR + l;
        bu[0][i] = U[off]; bx[0][i] = sv[off]; bv[0][i] = V[off];
        bm[0][i] = mask[b * SN + row0 + 8 * w + i];
    }

    #pragma unroll
    for (int s = 0; s < 2; s++) {
        const int cur = s & 1, nxt = cur ^ 1;
        const int nb = row0 + s * 64;
        // prefetch next stage (incl. mask) at stage TOP: full stage covers HBM
        if (s < 1) {
            #pragma unroll
            for (int i = 0; i < 8; i++) {
                const size_t off = rowbase + (size_t)(nb + 64 + 8 * w + i) * RR + l;
                bu[nxt][i] = U[off]; bx[nxt][i] = sv[off]; bv[nxt][i] = V[off];
                bm[nxt][i] = mask[b * SN + nb + 64 + 8 * w + i];
            }
        }
        float q[8], p[8];
        #pragma unroll
        for (int i = 0; i < 8; i++) {
            const float eu = __expf(bu[cur][i]);       // no-max softmax: N(0,1) inputs
            q[i] = eu * fastrcp(wave_sum64(eu));
        }
        #pragma unroll
        for (int i = 0; i < 8; i++) {
            p[i] = __expf(bx[cur][i] - 1e9f * (1.0f - bm[cur][i]));   // unnormalized K
            csum += p[i];
        }
        const uint4 ph = pack8(p);
        const uint4 vh = pack8(bv[cur]);
        const uint4 qh = pack8(q);
        const int wbase = (l << 5) + ((w ^ (l & 7)) << 2);
        if (s > 0) __syncthreads();     // prior stage's MFMA reads complete
        *(uint4*)(sm + PH + wbase) = ph;
        *(uint4*)(sm + VH + wbase) = vh;
        *(uint4*)(sm + QH + wbase) = qh;
        __syncthreads();
        #pragma unroll
        for (int ks = 0; ks < 2; ks++) {
            const int ub = ks * 4 + quad;
            s16x8 Ah[2], AQ[2];
            #pragma unroll
            for (int j = 0; j < 2; j++) {
                const int oa = swz((mi0 + j) * 16 + r15, ub);
                Ah[j] = ldfrag(sm + PH + oa);
                AQ[j] = ldfrag(sm + QH + oa);
            }
            const int ob = swz(ni * 16 + r15, ub);
            const s16x8 Bvh = ldfrag(sm + VH + ob);
            const s16x8 Bph = ldfrag(sm + PH + ob);
            const s16x8 Bq  = ldfrag(sm + QH + ob);
            #pragma unroll
            for (int j = 0; j < 2; j++) {
                aKV[j] = __builtin_amdgcn_mfma_f32_16x16x32_bf16(Ah[j], Bvh, aKV[j], 0, 0, 0);
                aSK[j] = __builtin_amdgcn_mfma_f32_16x16x32_bf16(Ah[j], Bph, aSK[j], 0, 0, 0);
                aSQ[j] = __builtin_amdgcn_mfma_f32_16x16x32_bf16(AQ[j], Bq,  aSQ[j], 0, 0, 0);
            }
        }
    }
    // streaming partial stores (no atomics — device-scope atomics serialize at
    // the cross-XCD coherence point; measured +14us in round 1)
    const size_t pb = ((size_t)bh * MCH + chunk) * 4096;
    #pragma unroll
    for (int j = 0; j < 2; j++)
        #pragma unroll
        for (int r = 0; r < 4; r++) {
            const int e = ((mi0 + j) * 16 + quad * 4 + r) * 64 + ni * 16 + r15;
            ktv_part[pb + e]  = aKV[j][r];
            symk_part[pb + e] = aSK[j][r];
            symq_part[pb + e] = aSQ[j][r];
        }
    __syncthreads();
    float* smf = (float*)sm;
    smf[w * 64 + l] = csum;
    __syncthreads();
    if (w == 0) {
        float scol = 0.f;
        #pragma unroll
        for (int j = 0; j < 8; j++) scol += smf[j * 64 + l];
        colsum_part[(bh * MCH + chunk) * 64 + l] = scol;
    }
}

// ---- finalize: grid (32,32) = 4 blk/CU; chunk-split halves, LDS combine ----
// Old version: 256 blocks = 1 blk/CU @ 4 waves (12% occ), 96 loads/thread ->
// latency-bound. New: 1024 blocks, 48 loads/thread, 16 waves/CU.
__global__ void k_finalize(const float* __restrict__ ktv_part, const float* __restrict__ symk_part,
                           const float* __restrict__ symq_part, const float* __restrict__ colsum_part,
                           const float* __restrict__ Sigma, const float* __restrict__ gammas,
                           unsigned short* __restrict__ ktvt_hi, unsigned short* __restrict__ ktvt_lo,
                           float* __restrict__ loss_part) {
    const int rb = blockIdx.x, bh = blockIdx.y, t = threadIdx.x;  // grid (32,32), 256 thr
    const int e = t & 127;            // element slot within block
    const int h = t >> 7;             // chunk half (0: ch 0..15, 1: ch 16..31)
    const int idx = rb * 128 + e;     // element within bh (0..4095)
    float kv = 0.f, sk = 0.f, sq = 0.f;
    #pragma unroll
    for (int cc = 0; cc < 16; cc++) {
        const int ch = h * 16 + cc;
        const size_t pb = ((size_t)bh * MCH + ch) * 4096 + idx;
        kv += ktv_part[pb]; sk += symk_part[pb]; sq += symq_part[pb];
    }
    // colsum: threads 0..127 cover 64 cols x 2 chunk-halves
    float csp = 0.f;
    if (t < 128) {
        const int col = t & 63, hc = t >> 6;
        #pragma unroll
        for (int cc = 0; cc < 16; cc++)
            csp += colsum_part[(bh * MCH + hc * 16 + cc) * 64 + col];
    }
    __shared__ float red[128][3];
    __shared__ float cs[64];
    __shared__ float smr[2];
    if (h == 1) { red[e][0] = kv; red[e][1] = sk; red[e][2] = sq; }
    if (t >= 64 && t < 128) cs[t - 64] = csp;
    __syncthreads();
    if (h == 0) { kv += red[e][0]; sk += red[e][1]; sq += red[e][2]; }
    if (t < 64) cs[t] += csp;
    __syncthreads();
    float lsum = 0.f;
    if (h == 0) {
        const int r = idx >> 6, c = idx & 63;
        const float iSr = fastrcp(cs[r]), iSc = fastrcp(cs[c]);
        const float g0 = gammas[0], g1 = gammas[1], g2 = gammas[2], g3 = gammas[3], g4 = gammas[4];
        const float sg = fastrcp(1.0f + __expf(-Sigma[bh * 64 + r]));
        float f = g4; f = f * sg + g3; f = f * sg + g2; f = f * sg + g1; f = f * sg + g0;
        const float kvf = kv * iSr * f;
        const unsigned short hi = f2bf(kvf);
        ktvt_hi[bh * 4096 + c * 64 + r] = hi;
        ktvt_lo[bh * 4096 + c * 64 + r] = f2bf(kvf - bf2f(hi));
        const float eye = (r == c) ? 1.0f : 0.0f;
        lsum = fabsf(sk * iSr * iSc - eye) + fabsf(sq - eye);
    }
    lsum = wave_sum(lsum);            // waves 2,3 contribute 0
    if ((t & 63) == 0 && t < 128) smr[t >> 6] = lsum;
    __syncthreads();
    if (t == 0) loss_part[bh * 32 + rb] = smr[0] + smr[1];
}

// ---- X = softmax(U) @ KtV' : octet mapping, vectorized loads/stores ----
// (512,4): the (512,8) carried through round 1 risked a 64-VGPR cap spill.
__launch_bounds__(512, 4)
__global__ void k_xq(const float* __restrict__ U,
                     const unsigned short* __restrict__ ktvt_hi,
                     const unsigned short* __restrict__ ktvt_lo,
                     const float* __restrict__ loss_part,
                     float* __restrict__ Xout, float* __restrict__ loss) {
    __shared__ __align__(16) unsigned int sm[4096];   // 2 buffers x Qh plane (16 KB)
    __shared__ float smr8[8];
    const int chunk = blockIdx.x, bh = blockIdx.y;
    const int t = threadIdx.x, l = t & 63, w = t >> 6;
    const int r15 = l & 15, quad = l >> 4;
    const int ni = w & 3, mi0 = (w >> 2) << 1;
    const size_t rowbase = (size_t)bh * SN * RR;
    const int row0 = chunk * XROWS;
    const int nl = 8 * w + (l >> 3);     // local row this thread owns (per stage)
    const int c0 = (l & 7) * 8;          // 8 consecutive r columns

    // final loss reduction: 1024 loss_part entries [bh][rb], b = entry>>8
    if (chunk == 0 && bh == 0) {
        float lv = loss_part[t * 2] + loss_part[t * 2 + 1];   // same b: 2t+1 never %256==0
        lv = wave_sum(lv);
        if ((t & 63) == 0) smr8[t >> 6] = lv;                 // wave w -> b = w>>1
    }

    s16x8 Bh[2], Bl[2];
    #pragma unroll
    for (int ks = 0; ks < 2; ks++) {
        const int idx = (ni * 16 + r15) * 64 + ks * 32 + quad * 8;
        Bh[ks] = __builtin_bit_cast(s16x8, *(const uint4*)(ktvt_hi + (size_t)bh * 4096 + idx));
        Bl[ks] = __builtin_bit_cast(s16x8, *(const uint4*)(ktvt_lo + (size_t)bh * 4096 + idx));
    }

    float4 ba[2], bb[2];
    {
        const float* src = U + rowbase + (size_t)(row0 + nl) * RR + c0;
        ba[0] = *(const float4*)src;
        bb[0] = *(const float4*)(src + 4);
    }

    #pragma unroll
    for (int s = 0; s < 2; s++) {
        const int cur = s & 1, nxt = cur ^ 1;
        const int nb = row0 + s * 64;
        const int bufb = cur * 2048;
        // prefetch at stage top: full-stage latency cover
        if (s < 1) {
            const float* src = U + rowbase + (size_t)(nb + 64 + nl) * RR + c0;
            ba[nxt] = *(const float4*)src;
            bb[nxt] = *(const float4*)(src + 4);
        }
        float e[8];
        e[0] = __expf(ba[cur].x); e[1] = __expf(ba[cur].y);
        e[2] = __expf(ba[cur].z); e[3] = __expf(ba[cur].w);
        e[4] = __expf(bb[cur].x); e[5] = __expf(bb[cur].y);
        e[6] = __expf(bb[cur].z); e[7] = __expf(bb[cur].w);
        float loc = 0.f;
        #pragma unroll
        for (int i = 0; i < 8; i++) loc += e[i];
        const float inv = fastrcp(octet_sum(loc));
        float q[8];
        #pragma unroll
        for (int i = 0; i < 8; i++) q[i] = e[i] * inv;
        *(uint4*)(sm + bufb + swz(nl, l & 7)) = pack8(q);
        __syncthreads();
        if (s == 0 && chunk == 0 && bh == 0 && t < 4)
            loss[t] = (REGC / (NH * 64.0f * 64.0f)) * (smr8[2 * t] + smr8[2 * t + 1]);
        f32x4 acc[2];
        acc[0] = (f32x4){0.f, 0.f, 0.f, 0.f};
        acc[1] = (f32x4){0.f, 0.f, 0.f, 0.f};
        #pragma unroll
        for (int ks = 0; ks < 2; ks++) {
            #pragma unroll
            for (int jj = 0; jj < 2; jj++) {
                const int oa = bufb + swz((mi0 + jj) * 16 + r15, ks * 4 + quad);
                const s16x8 Ah = ldfrag(sm + oa);
                acc[jj] = __builtin_amdgcn_mfma_f32_16x16x32_bf16(Ah, Bh[ks], acc[jj], 0, 0, 0);
                acc[jj] = __builtin_amdgcn_mfma_f32_16x16x32_bf16(Ah, Bl[ks], acc[jj], 0, 0, 0);
            }
        }
        #pragma unroll
        for (int jj = 0; jj < 2; jj++)
            #pragma unroll
            for (int r = 0; r < 4; r++) {
                const int n = nb + (mi0 + jj) * 16 + quad * 4 + r;
                __builtin_nontemporal_store(acc[jj][r],
                    &Xout[rowbase + (size_t)n * RR + ni * 16 + r15]);
            }
    }
}

extern "C" void kernel_launch(void* const* d_in, const int* in_sizes, int n_in,
                              void* d_out, int out_size, void* d_ws, size_t ws_size,
                              hipStream_t stream) {
    (void)in_sizes; (void)n_in; (void)out_size; (void)ws_size;
    const float* U      = (const float*)d_in[0];
    const float* Sigma  = (const float*)d_in[1];
    const float* sv     = (const float*)d_in[2];
    const float* V      = (const float*)d_in[3];
    const float* mask   = (const float*)d_in[4];
    const float* gammas = (const float*)d_in[5];

    float* X    = (float*)d_out;                 // [32][4096][64]
    float* loss = X + (size_t)BHN * SN * RR;     // [4]

    float* ws          = (float*)d_ws;
    float* ktv_part    = ws;                                    // 4194304
    float* symk_part   = ktv_part + (size_t)BHN * MCH * 4096;   // 4194304
    float* symq_part   = symk_part + (size_t)BHN * MCH * 4096;  // 4194304
    float* colsum_part = symq_part + (size_t)BHN * MCH * 4096;  // 65536
    float* loss_part   = colsum_part + BHN * MCH * 64;          // 1024
    unsigned short* ktvt_hi = (unsigned short*)(loss_part + 1024);
    unsigned short* ktvt_lo = ktvt_hi + BHN * 4096;

    hipLaunchKernelGGL(k_main, dim3(MCH, BHN), dim3(512), 0, stream,
                       U, sv, V, mask, ktv_part, symk_part, symq_part, colsum_part);
    hipLaunchKernelGGL(k_finalize, dim3(32, BHN), dim3(256), 0, stream,
                       ktv_part, symk_part, symq_part, colsum_part, Sigma, gammas,
                       ktvt_hi, ktvt_lo, loss_part);
    hipLaunchKernelGGL(k_xq, dim3(XCH, BHN), dim3(512), 0, stream,
                       U, ktvt_hi, ktvt_lo, loss_part, X, loss);
}

// Round 6
// 158.567 us; speedup vs baseline: 1.0604x; 1.0604x over previous
//
#include <hip/hip_runtime.h>
#include <math.h>

// Problem constants (B=4, H=8, N=4096, R=d=64)
#define NB 4
#define NH 8
#define BHN 32
#define SN 4096
#define RR 64
#define REGC 0.1f

#define MCH 16        // k_main chunks per bh (grid 512)
#define MROWS 256     // rows per k_main block (4 stages of 64)
#define XCH 32        // k_xq chunks per bh (grid 1024)
#define XROWS 128     // rows per k_xq block (2 stages of 64)

typedef short s16x8 __attribute__((ext_vector_type(8)));
typedef float f32x4 __attribute__((ext_vector_type(4)));

__device__ __forceinline__ float wave_sum(float v) {     // loss reductions only
    #pragma unroll
    for (int off = 32; off; off >>= 1) v += __shfl_xor(v, off, 64);
    return v;
}
// 64-lane sum: 4 DPP row-rotate adds (VALU pipe) + 2 shuffles (LDS pipe)
__device__ __forceinline__ float wave_sum64(float v) {
    v += __int_as_float(__builtin_amdgcn_update_dpp(0, __float_as_int(v), 0x121, 0xf, 0xf, true));
    v += __int_as_float(__builtin_amdgcn_update_dpp(0, __float_as_int(v), 0x122, 0xf, 0xf, true));
    v += __int_as_float(__builtin_amdgcn_update_dpp(0, __float_as_int(v), 0x124, 0xf, 0xf, true));
    v += __int_as_float(__builtin_amdgcn_update_dpp(0, __float_as_int(v), 0x128, 0xf, 0xf, true));
    v += __shfl_xor(v, 16, 64);
    v += __shfl_xor(v, 32, 64);
    return v;
}
// 8-lane octet sum (lanes sharing l>>3): quad_perm xor1, xor2 (VALU) + shfl 4
__device__ __forceinline__ float octet_sum(float v) {
    v += __int_as_float(__builtin_amdgcn_update_dpp(0, __float_as_int(v), 0xB1, 0xf, 0xf, true));
    v += __int_as_float(__builtin_amdgcn_update_dpp(0, __float_as_int(v), 0x4E, 0xf, 0xf, true));
    v += __shfl_xor(v, 4, 64);
    return v;
}
// fast reciprocal: v_rcp_f32 (~1ulp) instead of full IEEE div sequence
__device__ __forceinline__ float fastrcp(float x) {
    float r; asm("v_rcp_f32 %0, %1" : "=v"(r) : "v"(x)); return r;
}
__device__ __forceinline__ unsigned short f2bf(float x) {   // manual RNE (finalize hi/lo)
    unsigned int u = __float_as_uint(x);
    u += 0x7FFFu + ((u >> 16) & 1u);
    return (unsigned short)(u >> 16);
}
__device__ __forceinline__ float bf2f(unsigned short h) {
    return __uint_as_float(((unsigned int)h) << 16);
}
// HW packed f32->bf16 RNE convert: 1 instr replaces ~10 VALU ops of manual f2bf
__device__ __forceinline__ unsigned int pkbf(float lo, float hi) {
    unsigned int r;
    asm("v_cvt_pk_bf16_f32 %0, %1, %2" : "=v"(r) : "v"(lo), "v"(hi));
    return r;
}
__device__ __forceinline__ s16x8 ldfrag(const unsigned int* p) {
    uint4 r = *(const uint4*)p;
    return __builtin_bit_cast(s16x8, r);
}
// row-major [64 rows][64 bf16], rowstride 32 uints, 16B-block XOR swizzle
__device__ __forceinline__ int swz(int row, int blk) {
    return (row << 5) + (((blk ^ (row & 7))) << 2);
}
__device__ __forceinline__ uint4 pack8(const float* x) {
    return make_uint4(pkbf(x[0], x[1]), pkbf(x[2], x[3]),
                      pkbf(x[4], x[5]), pkbf(x[6], x[7]));
}

// ---- fused main reduction: dbuf 48 KB, 4 stages, COLUMN layout ----
// LDS planes store the TRANSPOSE [r][n] (thread owns col l, rows 8w..8w+7 ->
// write at swz(l, w)): the k_main MFMAs contract over n, so n must be the
// fast/in-block LDS dim for both fragments. (Octet [n][r] layout = round-5
// correctness failure; only valid in k_xq where contraction is over r.)
// launch_bounds(512,4): 128-VGPR cap ((512,8) spills ~50 MB, measured round 2).
#define PH 0
#define VH 2048
#define QH 4096
__launch_bounds__(512, 4)
__global__ void k_main(const float* __restrict__ U, const float* __restrict__ sv,
                       const float* __restrict__ V, const float* __restrict__ mask,
                       float* __restrict__ ktv_part, float* __restrict__ symk_part,
                       float* __restrict__ symq_part, float* __restrict__ colsum_part) {
    __shared__ __align__(16) unsigned int sm[12288];   // 48 KB
    const int chunk = blockIdx.x, bh = blockIdx.y, b = bh >> 3;
    const int t = threadIdx.x, l = t & 63, w = t >> 6;
    const int r15 = l & 15, quad = l >> 4;
    const int ni = w & 3, mi0 = (w >> 2) << 1;
    const size_t rowbase = (size_t)bh * SN * RR;
    const int row0 = chunk * MROWS;

    float csum = 0.0f;
    f32x4 aKV[2], aSK[2], aSQ[2];
    #pragma unroll
    for (int j = 0; j < 2; j++) {
        aKV[j] = (f32x4){0.f, 0.f, 0.f, 0.f};
        aSK[j] = (f32x4){0.f, 0.f, 0.f, 0.f};
        aSQ[j] = (f32x4){0.f, 0.f, 0.f, 0.f};
    }

    float bu[2][8], bx[2][8], bv[2][8], bm[2][8];
    #pragma unroll
    for (int i = 0; i < 8; i++) {
        const size_t off = rowbase + (size_t)(row0 + 8 * w + i) * RR + l;
        bu[0][i] = __builtin_nontemporal_load(&U[off]);
        bx[0][i] = __builtin_nontemporal_load(&sv[off]);
        bv[0][i] = __builtin_nontemporal_load(&V[off]);
        bm[0][i] = mask[b * SN + row0 + 8 * w + i];
    }

    #pragma unroll
    for (int s = 0; s < 4; s++) {
        const int cur = s & 1, nxt = cur ^ 1;
        const int nb = row0 + s * 64;
        const int bufb = cur * 6144;
        // prefetch next stage (incl. mask) at stage TOP: full stage of compute
        // covers the HBM latency; mid-stage mask load was an unhidden stall.
        if (s < 3) {
            #pragma unroll
            for (int i = 0; i < 8; i++) {
                const size_t off = rowbase + (size_t)(nb + 64 + 8 * w + i) * RR + l;
                bu[nxt][i] = __builtin_nontemporal_load(&U[off]);
                bx[nxt][i] = __builtin_nontemporal_load(&sv[off]);
                bv[nxt][i] = __builtin_nontemporal_load(&V[off]);
                bm[nxt][i] = mask[b * SN + nb + 64 + 8 * w + i];
            }
        }
        float q[8], p[8];
        #pragma unroll
        for (int i = 0; i < 8; i++) {
            const float eu = __expf(bu[cur][i]);       // no-max softmax: N(0,1) inputs
            q[i] = eu * fastrcp(wave_sum64(eu));
        }
        #pragma unroll
        for (int i = 0; i < 8; i++) {
            p[i] = __expf(bx[cur][i] - 1e9f * (1.0f - bm[cur][i]));   // unnormalized K
            csum += p[i];
        }
        const uint4 ph = pack8(p);
        const uint4 vh = pack8(bv[cur]);
        const uint4 qh = pack8(q);
        const int wbase = bufb + (l << 5) + ((w ^ (l & 7)) << 2);
        *(uint4*)(sm + PH + wbase) = ph;
        *(uint4*)(sm + VH + wbase) = vh;
        *(uint4*)(sm + QH + wbase) = qh;
        __syncthreads();      // one barrier/stage: double buffer makes it safe
        #pragma unroll
        for (int ks = 0; ks < 2; ks++) {
            const int ub = ks * 4 + quad;
            s16x8 Ah[2], AQ[2];
            #pragma unroll
            for (int j = 0; j < 2; j++) {
                const int oa = bufb + swz((mi0 + j) * 16 + r15, ub);
                Ah[j] = ldfrag(sm + PH + oa);
                AQ[j] = ldfrag(sm + QH + oa);
            }
            const int ob = bufb + swz(ni * 16 + r15, ub);
            const s16x8 Bvh = ldfrag(sm + VH + ob);
            const s16x8 Bph = ldfrag(sm + PH + ob);
            const s16x8 Bq  = ldfrag(sm + QH + ob);
            #pragma unroll
            for (int j = 0; j < 2; j++) {
                aKV[j] = __builtin_amdgcn_mfma_f32_16x16x32_bf16(Ah[j], Bvh, aKV[j], 0, 0, 0);
                aSK[j] = __builtin_amdgcn_mfma_f32_16x16x32_bf16(Ah[j], Bph, aSK[j], 0, 0, 0);
                aSQ[j] = __builtin_amdgcn_mfma_f32_16x16x32_bf16(AQ[j], Bq,  aSQ[j], 0, 0, 0);
            }
        }
    }
    // streaming partial stores (no atomics — device-scope atomics serialize at
    // the cross-XCD coherence point; measured +14us in round 1)
    const size_t pb = ((size_t)bh * MCH + chunk) * 4096;
    #pragma unroll
    for (int j = 0; j < 2; j++)
        #pragma unroll
        for (int r = 0; r < 4; r++) {
            const int e = ((mi0 + j) * 16 + quad * 4 + r) * 64 + ni * 16 + r15;
            ktv_part[pb + e]  = aKV[j][r];
            symk_part[pb + e] = aSK[j][r];
            symq_part[pb + e] = aSQ[j][r];
        }
    __syncthreads();
    float* smf = (float*)sm;
    smf[w * 64 + l] = csum;
    __syncthreads();
    if (w == 0) {
        float scol = 0.f;
        #pragma unroll
        for (int j = 0; j < 8; j++) scol += smf[j * 64 + l];
        colsum_part[(bh * MCH + chunk) * 64 + l] = scol;
    }
}

// ---- finalize: grid (32,32) = 4 blk/CU; chunk-split halves, LDS combine ----
__global__ void k_finalize(const float* __restrict__ ktv_part, const float* __restrict__ symk_part,
                           const float* __restrict__ symq_part, const float* __restrict__ colsum_part,
                           const float* __restrict__ Sigma, const float* __restrict__ gammas,
                           unsigned short* __restrict__ ktvt_hi, unsigned short* __restrict__ ktvt_lo,
                           float* __restrict__ loss_part) {
    const int rb = blockIdx.x, bh = blockIdx.y, t = threadIdx.x;  // grid (32,32), 256 thr
    const int e = t & 127;            // element slot within block
    const int h = t >> 7;             // chunk half (0: ch 0..7, 1: ch 8..15)
    const int idx = rb * 128 + e;     // element within bh (0..4095)
    float kv = 0.f, sk = 0.f, sq = 0.f;
    #pragma unroll
    for (int cc = 0; cc < 8; cc++) {
        const int ch = h * 8 + cc;
        const size_t pb = ((size_t)bh * MCH + ch) * 4096 + idx;
        kv += ktv_part[pb]; sk += symk_part[pb]; sq += symq_part[pb];
    }
    // colsum: threads 0..127 cover 64 cols x 2 chunk-halves
    float csp = 0.f;
    if (t < 128) {
        const int col = t & 63, hc = t >> 6;
        #pragma unroll
        for (int cc = 0; cc < 8; cc++)
            csp += colsum_part[(bh * MCH + hc * 8 + cc) * 64 + col];
    }
    __shared__ float red[128][3];
    __shared__ float cs[64];
    __shared__ float smr[2];
    if (h == 1) { red[e][0] = kv; red[e][1] = sk; red[e][2] = sq; }
    if (t >= 64 && t < 128) cs[t - 64] = csp;
    __syncthreads();
    if (h == 0) { kv += red[e][0]; sk += red[e][1]; sq += red[e][2]; }
    if (t < 64) cs[t] += csp;
    __syncthreads();
    float lsum = 0.f;
    if (h == 0) {
        const int r = idx >> 6, c = idx & 63;
        const float iSr = fastrcp(cs[r]), iSc = fastrcp(cs[c]);
        const float g0 = gammas[0], g1 = gammas[1], g2 = gammas[2], g3 = gammas[3], g4 = gammas[4];
        const float sg = fastrcp(1.0f + __expf(-Sigma[bh * 64 + r]));
        float f = g4; f = f * sg + g3; f = f * sg + g2; f = f * sg + g1; f = f * sg + g0;
        const float kvf = kv * iSr * f;
        const unsigned short hi = f2bf(kvf);
        ktvt_hi[bh * 4096 + c * 64 + r] = hi;
        ktvt_lo[bh * 4096 + c * 64 + r] = f2bf(kvf - bf2f(hi));
        const float eye = (r == c) ? 1.0f : 0.0f;
        lsum = fabsf(sk * iSr * iSc - eye) + fabsf(sq - eye);
    }
    lsum = wave_sum(lsum);            // waves 2,3 contribute 0
    if ((t & 63) == 0 && t < 128) smr[t >> 6] = lsum;
    __syncthreads();
    if (t == 0) loss_part[bh * 32 + rb] = smr[0] + smr[1];
}

// ---- X = softmax(U) @ KtV' : octet mapping, vectorized loads/stores ----
__launch_bounds__(512, 4)
__global__ void k_xq(const float* __restrict__ U,
                     const unsigned short* __restrict__ ktvt_hi,
                     const unsigned short* __restrict__ ktvt_lo,
                     const float* __restrict__ loss_part,
                     float* __restrict__ Xout, float* __restrict__ loss) {
    __shared__ __align__(16) unsigned int sm[4096];   // 2 buffers x Qh plane (16 KB)
    __shared__ float smr8[8];
    const int chunk = blockIdx.x, bh = blockIdx.y;
    const int t = threadIdx.x, l = t & 63, w = t >> 6;
    const int r15 = l & 15, quad = l >> 4;
    const int ni = w & 3, mi0 = (w >> 2) << 1;
    const size_t rowbase = (size_t)bh * SN * RR;
    const int row0 = chunk * XROWS;
    const int nl = 8 * w + (l >> 3);     // local row this thread owns (per stage)
    const int c0 = (l & 7) * 8;          // 8 consecutive r columns

    // final loss reduction: 1024 loss_part entries [bh][rb], b = entry>>8
    if (chunk == 0 && bh == 0) {
        float lv = loss_part[t * 2] + loss_part[t * 2 + 1];   // wave w -> b = w>>1
        lv = wave_sum(lv);
        if ((t & 63) == 0) smr8[t >> 6] = lv;
    }

    s16x8 Bh[2], Bl[2];
    #pragma unroll
    for (int ks = 0; ks < 2; ks++) {
        const int idx = (ni * 16 + r15) * 64 + ks * 32 + quad * 8;
        Bh[ks] = __builtin_bit_cast(s16x8, *(const uint4*)(ktvt_hi + (size_t)bh * 4096 + idx));
        Bl[ks] = __builtin_bit_cast(s16x8, *(const uint4*)(ktvt_lo + (size_t)bh * 4096 + idx));
    }

    float4 ba[2], bb[2];
    {
        const float* src = U + rowbase + (size_t)(row0 + nl) * RR + c0;
        ba[0] = *(const float4*)src;
        bb[0] = *(const float4*)(src + 4);
    }

    #pragma unroll
    for (int s = 0; s < 2; s++) {
        const int cur = s & 1, nxt = cur ^ 1;
        const int nb = row0 + s * 64;
        const int bufb = cur * 2048;
        // prefetch at stage top: full-stage latency cover
        if (s < 1) {
            const float* src = U + rowbase + (size_t)(nb + 64 + nl) * RR + c0;
            ba[nxt] = *(const float4*)src;
            bb[nxt] = *(const float4*)(src + 4);
        }
        float e[8];
        e[0] = __expf(ba[cur].x); e[1] = __expf(ba[cur].y);
        e[2] = __expf(ba[cur].z); e[3] = __expf(ba[cur].w);
        e[4] = __expf(bb[cur].x); e[5] = __expf(bb[cur].y);
        e[6] = __expf(bb[cur].z); e[7] = __expf(bb[cur].w);
        float loc = 0.f;
        #pragma unroll
        for (int i = 0; i < 8; i++) loc += e[i];
        const float inv = fastrcp(octet_sum(loc));
        #pragma unroll
        for (int i = 0; i < 8; i++) e[i] *= inv;
        *(uint4*)(sm + bufb + swz(nl, l & 7)) = pack8(e);
        __syncthreads();
        if (s == 0 && chunk == 0 && bh == 0 && t < 4)
            loss[t] = (REGC / (NH * 64.0f * 64.0f)) * (smr8[2 * t] + smr8[2 * t + 1]);
        f32x4 acc[2];
        acc[0] = (f32x4){0.f, 0.f, 0.f, 0.f};
        acc[1] = (f32x4){0.f, 0.f, 0.f, 0.f};
        #pragma unroll
        for (int ks = 0; ks < 2; ks++) {
            #pragma unroll
            for (int jj = 0; jj < 2; jj++) {
                const int oa = bufb + swz((mi0 + jj) * 16 + r15, ks * 4 + quad);
                const s16x8 Ah = ldfrag(sm + oa);
                acc[jj] = __builtin_amdgcn_mfma_f32_16x16x32_bf16(Ah, Bh[ks], acc[jj], 0, 0, 0);
                acc[jj] = __builtin_amdgcn_mfma_f32_16x16x32_bf16(Ah, Bl[ks], acc[jj], 0, 0, 0);
            }
        }
        #pragma unroll
        for (int jj = 0; jj < 2; jj++)
            #pragma unroll
            for (int r = 0; r < 4; r++) {
                const int n = nb + (mi0 + jj) * 16 + quad * 4 + r;
                __builtin_nontemporal_store(acc[jj][r],
                    &Xout[rowbase + (size_t)n * RR + ni * 16 + r15]);
            }
    }
}

extern "C" void kernel_launch(void* const* d_in, const int* in_sizes, int n_in,
                              void* d_out, int out_size, void* d_ws, size_t ws_size,
                              hipStream_t stream) {
    (void)in_sizes; (void)n_in; (void)out_size; (void)ws_size;
    const float* U      = (const float*)d_in[0];
    const float* Sigma  = (const float*)d_in[1];
    const float* sv     = (const float*)d_in[2];
    const float* V      = (const float*)d_in[3];
    const float* mask   = (const float*)d_in[4];
    const float* gammas = (const float*)d_in[5];

    float* X    = (float*)d_out;                 // [32][4096][64]
    float* loss = X + (size_t)BHN * SN * RR;     // [4]

    float* ws          = (float*)d_ws;
    float* ktv_part    = ws;                                    // 2097152
    float* symk_part   = ktv_part + (size_t)BHN * MCH * 4096;   // 2097152
    float* symq_part   = symk_part + (size_t)BHN * MCH * 4096;  // 2097152
    float* colsum_part = symq_part + (size_t)BHN * MCH * 4096;  // 32768
    float* loss_part   = colsum_part + BHN * MCH * 64;          // 1024
    unsigned short* ktvt_hi = (unsigned short*)(loss_part + 1024);
    unsigned short* ktvt_lo = ktvt_hi + BHN * 4096;

    hipLaunchKernelGGL(k_main, dim3(MCH, BHN), dim3(512), 0, stream,
                       U, sv, V, mask, ktv_part, symk_part, symq_part, colsum_part);
    hipLaunchKernelGGL(k_finalize, dim3(32, BHN), dim3(256), 0, stream,
                       ktv_part, symk_part, symq_part, colsum_part, Sigma, gammas,
                       ktvt_hi, ktvt_lo, loss_part);
    hipLaunchKernelGGL(k_xq, dim3(XCH, BHN), dim3(512), 0, stream,
                       U, ktvt_hi, ktvt_lo, loss_part, X, loss);
}